// Round 2
// baseline (651.995 us; speedup 1.0000x reference)
//
#include <hip/hip_runtime.h>
#include <hip/hip_cooperative_groups.h>

namespace cg = cooperative_groups;

typedef __attribute__((ext_vector_type(8))) _Float16 half8;
typedef __attribute__((ext_vector_type(2))) _Float16 half2v;
typedef _Float16 half_t;

// Problem constants (B=16, N=M=1024, D=256)
#define EPS_F      0.1f
#define INV_EPS_F  10.0f
#define LOG_MU_F  -6.9314616f   /* log(1/1024 + 1e-8) */
#define LOG_NU_F  -6.9314616f
#define ERR_STOP   1.6f         /* thresh 0.1 * 16 batches (errAcc holds sum over batches) */
#define MAX_ITER   100

// ---------------- K1: inverse row norms of x and y ----------------
__global__ __launch_bounds__(256) void mfa_norms(const float* __restrict__ x,
                                                 const float* __restrict__ y,
                                                 float* __restrict__ invnx,
                                                 float* __restrict__ invny) {
  int wave = (blockIdx.x * 256 + threadIdx.x) >> 6;   // 0..511
  int lane = threadIdx.x & 63;
  for (int row = wave; row < 32768; row += 512) {
    const float* src = (row < 16384) ? (x + (size_t)row * 256)
                                     : (y + (size_t)(row - 16384) * 256);
    float4 vv = ((const float4*)src)[lane];           // 256 floats = 64 lanes x float4
    float ss = vv.x*vv.x + vv.y*vv.y + vv.z*vv.z + vv.w*vv.w;
    #pragma unroll
    for (int off = 32; off; off >>= 1) ss += __shfl_xor(ss, off);
    if (lane == 0) {
      float inv = 1.0f / fmaxf(sqrtf(ss), 1e-8f);
      if (row < 16384) invnx[row] = inv; else invny[row - 16384] = inv;
    }
  }
}

// ---------------- K2: E(fp16) = 1 - invnx*invny*(x . y^T), 128x128 tiles ----------------
__global__ __launch_bounds__(256) void mfa_gemm(const float* __restrict__ X,
                                                const float* __restrict__ Y,
                                                const float* __restrict__ invnx,
                                                const float* __restrict__ invny,
                                                half_t* __restrict__ Eh) {
  const int b = blockIdx.z;
  const int rowBase = blockIdx.y * 128;
  const int colBase = blockIdx.x * 128;
  const float* Xb = X + (size_t)b * 262144;   // 1024*256
  const float* Yb = Y + (size_t)b * 262144;

  __shared__ float Xs[16][129];
  __shared__ float Ys[16][129];

  const int t = threadIdx.x;
  const int tx = t & 15, ty = t >> 4;

  float acc[8][8];
  #pragma unroll
  for (int i = 0; i < 8; ++i)
    #pragma unroll
    for (int j = 0; j < 8; ++j) acc[i][j] = 0.0f;

  for (int k0 = 0; k0 < 256; k0 += 16) {
    #pragma unroll
    for (int l = 0; l < 2; ++l) {
      int f = t + l * 256;          // 0..511
      int r = f >> 2;               // 0..127
      int k4 = f & 3;               // float4 slot within 16 k's
      float4 xv = *(const float4*)(Xb + (size_t)(rowBase + r) * 256 + k0 + k4 * 4);
      Xs[k4*4+0][r] = xv.x; Xs[k4*4+1][r] = xv.y;
      Xs[k4*4+2][r] = xv.z; Xs[k4*4+3][r] = xv.w;
      float4 yv = *(const float4*)(Yb + (size_t)(colBase + r) * 256 + k0 + k4 * 4);
      Ys[k4*4+0][r] = yv.x; Ys[k4*4+1][r] = yv.y;
      Ys[k4*4+2][r] = yv.z; Ys[k4*4+3][r] = yv.w;
    }
    __syncthreads();
    #pragma unroll
    for (int k = 0; k < 16; ++k) {
      float a[8], bb[8];
      #pragma unroll
      for (int i = 0; i < 8; ++i) a[i] = Xs[k][ty*8 + i];
      #pragma unroll
      for (int j = 0; j < 8; ++j) bb[j] = Ys[k][tx*8 + j];
      #pragma unroll
      for (int i = 0; i < 8; ++i)
        #pragma unroll
        for (int j = 0; j < 8; ++j) acc[i][j] += a[i] * bb[j];
    }
    __syncthreads();
  }

  float sy[8];
  #pragma unroll
  for (int j = 0; j < 8; ++j) sy[j] = invny[b*1024 + colBase + tx*8 + j];
  #pragma unroll
  for (int i = 0; i < 8; ++i) {
    int row = rowBase + ty*8 + i;
    float sx = invnx[b*1024 + row];
    half8 h;
    #pragma unroll
    for (int j = 0; j < 8; ++j)
      h[j] = (_Float16)(1.0f - acc[i][j] * sx * sy[j]);
    *(half8*)(Eh + (((size_t)b << 10) + row) * 1024 + colBase + tx*8) = h;
  }
}

// ---------------- shared device bodies (512 blocks x 256 threads) ----------------

// Row pass: u_new = eps*(log_mu - log sum_m exp((v_m - E[n,m])/eps)).
// 32 rows per block, 8 per wave. Returns per-wave |du| partial (valid on lane 0).
__device__ __forceinline__ float rowpass_body(const half_t* __restrict__ Eh,
                                              const float* __restrict__ v,
                                              float* __restrict__ u, int blk) {
  const int t = threadIdx.x, w = t >> 6, lane = t & 63;
  const int bA = blk >> 5;                       // 32 blocks per batch
  const float4* vb4 = (const float4*)(v + (bA << 10));
  float werr = 0.0f;
  #pragma unroll
  for (int r = 0; r < 8; ++r) {
    const int row = (blk << 5) + (w << 3) + r;   // 0..16383
    const half8* E8 = (const half8*)(Eh + ((size_t)row << 10));
    float s = 0.0f;
    #pragma unroll
    for (int q = 0; q < 2; ++q) {
      const int idx = lane + (q << 6);           // 0..127 half8 chunks
      half8 e8 = E8[idx];
      float4 v0 = vb4[idx * 2];
      float4 v1 = vb4[idx * 2 + 1];
      s += __expf((v0.x - (float)e8[0]) * INV_EPS_F);
      s += __expf((v0.y - (float)e8[1]) * INV_EPS_F);
      s += __expf((v0.z - (float)e8[2]) * INV_EPS_F);
      s += __expf((v0.w - (float)e8[3]) * INV_EPS_F);
      s += __expf((v1.x - (float)e8[4]) * INV_EPS_F);
      s += __expf((v1.y - (float)e8[5]) * INV_EPS_F);
      s += __expf((v1.z - (float)e8[6]) * INV_EPS_F);
      s += __expf((v1.w - (float)e8[7]) * INV_EPS_F);
    }
    #pragma unroll
    for (int off = 32; off; off >>= 1) s += __shfl_xor(s, off);
    if (lane == 0) {
      float unew = EPS_F * (LOG_MU_F - __logf(s));
      werr += fabsf(unew - u[row]);
      u[row] = unew;
    }
  }
  return werr;
}

// Column partial sums: 512 blocks = 16 batches x 16 n-segments(64 rows) x 2 m-halves.
__device__ __forceinline__ void colpass_body(const half_t* __restrict__ Eh,
                                             const float* __restrict__ u,
                                             float* __restrict__ partials, int blk) {
  const int t = threadIdx.x;
  const int b = blk >> 5, sub = blk & 31;
  const int seg = sub & 15, ct = sub >> 4;       // seg 0..15, ct 0..1
  const int m0 = (ct << 9) + (t << 1);           // even m, 2 per thread
  const float* ub = u + (b << 10);
  const half_t* Eb = Eh + ((size_t)b << 20);
  float p0 = 0.0f, p1 = 0.0f;
  const int n0 = seg << 6;
  #pragma unroll 4
  for (int n = n0; n < n0 + 64; ++n) {
    float un = ub[n];
    half2v e2 = *(const half2v*)(Eb + ((size_t)n << 10) + m0);
    p0 += __expf((un - (float)e2[0]) * INV_EPS_F);
    p1 += __expf((un - (float)e2[1]) * INV_EPS_F);
  }
  float2 pr; pr.x = p0; pr.y = p1;
  *(float2*)(partials + ((((b << 4) + seg) << 10) + m0)) = pr;
}

// Merge partials -> v, one thread per (b,m), g in [0,16384)
__device__ __forceinline__ void merge_body(const float* __restrict__ partials,
                                           float* __restrict__ v, int g) {
  const int b = g >> 10, m = g & 1023;
  float tot = 0.0f;
  #pragma unroll
  for (int seg = 0; seg < 16; ++seg)
    tot += partials[(((b << 4) + seg) << 10) + m];
  v[g] = EPS_F * (LOG_NU_F - __logf(tot));
}

// Cost pass partial: returns per-wave sum (valid on lane 0)
__device__ __forceinline__ float cost_body(const half_t* __restrict__ Eh,
                                           const float* __restrict__ u,
                                           const float* __restrict__ v, int blk) {
  const int t = threadIdx.x, w = t >> 6, lane = t & 63;
  const int bA = blk >> 5;
  const float4* vb4 = (const float4*)(v + (bA << 10));
  float cacc = 0.0f;
  #pragma unroll
  for (int r = 0; r < 8; ++r) {
    const int row = (blk << 5) + (w << 3) + r;
    const float un = u[row];
    const half8* E8 = (const half8*)(Eh + ((size_t)row << 10));
    #pragma unroll
    for (int q = 0; q < 2; ++q) {
      const int idx = lane + (q << 6);
      half8 e8 = E8[idx];
      float4 v0 = vb4[idx * 2];
      float4 v1 = vb4[idx * 2 + 1];
      float e;
      e = (float)e8[0]; cacc += __expf((un + v0.x - e) * INV_EPS_F) * e;
      e = (float)e8[1]; cacc += __expf((un + v0.y - e) * INV_EPS_F) * e;
      e = (float)e8[2]; cacc += __expf((un + v0.z - e) * INV_EPS_F) * e;
      e = (float)e8[3]; cacc += __expf((un + v0.w - e) * INV_EPS_F) * e;
      e = (float)e8[4]; cacc += __expf((un + v1.x - e) * INV_EPS_F) * e;
      e = (float)e8[5]; cacc += __expf((un + v1.y - e) * INV_EPS_F) * e;
      e = (float)e8[6]; cacc += __expf((un + v1.z - e) * INV_EPS_F) * e;
      e = (float)e8[7]; cacc += __expf((un + v1.w - e) * INV_EPS_F) * e;
    }
  }
  #pragma unroll
  for (int off = 32; off; off >>= 1) cacc += __shfl_xor(cacc, off);
  return cacc;
}

// ---------------- K3a: cooperative Sinkhorn (preferred path) ----------------
__global__ __launch_bounds__(256, 2) void mfa_sinkhorn_coop(
    const half_t* __restrict__ Eh, float* __restrict__ u, float* __restrict__ v,
    float* __restrict__ partials, float* __restrict__ errAcc,
    float* __restrict__ cost) {
  cg::grid_group grid = cg::this_grid();
  const int t = threadIdx.x, blk = blockIdx.x;   // 512 blocks
  const int g = blk * 256 + t;
  const int w = t >> 6, lane = t & 63;
  __shared__ float lred[4];

  // per-call init (harness poisons buffers)
  if (g < 16384)      u[g] = 0.0f;
  else if (g < 32768) v[g - 16384] = 0.0f;
  else if (g < 32896) errAcc[g - 32768] = 0.0f;
  else if (g < 32912) cost[g - 32896] = 0.0f;
  grid.sync();

  for (int it = 0; it < MAX_ITER; ++it) {
    float we = rowpass_body(Eh, v, u, blk);
    if (lane == 0) lred[w] = we;
    __syncthreads();
    if (t == 0) atomicAdd(&errAcc[it], lred[0] + lred[1] + lred[2] + lred[3]);
    grid.sync();

    colpass_body(Eh, u, partials, blk);
    grid.sync();

    if (g < 16384) merge_body(partials, v, g);
    grid.sync();

    float err = __hip_atomic_load(&errAcc[it], __ATOMIC_RELAXED,
                                  __HIP_MEMORY_SCOPE_AGENT);
    if (err < ERR_STOP) break;   // uniform: all blocks read same value
  }

  float cc = cost_body(Eh, u, v, blk);
  if (lane == 0) lred[w] = cc;
  __syncthreads();
  if (t == 0) atomicAdd(&cost[blk >> 5], lred[0] + lred[1] + lred[2] + lred[3]);
}

// ---------------- K3b: non-cooperative fallback ----------------
__global__ __launch_bounds__(256) void fb_init(float* __restrict__ u,
                                               float* __restrict__ v,
                                               float* __restrict__ errAcc,
                                               int* __restrict__ done,
                                               float* __restrict__ cost) {
  int g = blockIdx.x * 256 + threadIdx.x;
  if (g < 16384)      u[g] = 0.0f;
  else if (g < 32768) v[g - 16384] = 0.0f;
  else if (g < 32896) errAcc[g - 32768] = 0.0f;
  else if (g < 32912) cost[g - 32896] = 0.0f;
  if (g == 0) *done = 0;
}

__global__ __launch_bounds__(256) void fb_rowpass(const half_t* __restrict__ Eh,
                                                  const float* __restrict__ v,
                                                  float* __restrict__ u,
                                                  float* __restrict__ errAcc,
                                                  const int* __restrict__ done,
                                                  int it) {
  if (*done) return;
  __shared__ float lred[4];
  const int t = threadIdx.x, w = t >> 6, lane = t & 63;
  float we = rowpass_body(Eh, v, u, blockIdx.x);
  if (lane == 0) lred[w] = we;
  __syncthreads();
  if (t == 0) atomicAdd(&errAcc[it], lred[0] + lred[1] + lred[2] + lred[3]);
}

__global__ __launch_bounds__(256) void fb_colpass(const half_t* __restrict__ Eh,
                                                  const float* __restrict__ u,
                                                  float* __restrict__ partials,
                                                  const int* __restrict__ done) {
  if (*done) return;
  colpass_body(Eh, u, partials, blockIdx.x);
}

__global__ __launch_bounds__(256) void fb_merge(const float* __restrict__ partials,
                                                float* __restrict__ v,
                                                const int* __restrict__ done) {
  if (*done) return;
  merge_body(partials, v, blockIdx.x * 256 + threadIdx.x);
}

__global__ void fb_check(const float* __restrict__ errAcc, int* __restrict__ done,
                         int it) {
  if (threadIdx.x == 0 && errAcc[it] < ERR_STOP) *done = 1;
}

__global__ __launch_bounds__(256) void fb_cost(const half_t* __restrict__ Eh,
                                               const float* __restrict__ u,
                                               const float* __restrict__ v,
                                               float* __restrict__ cost) {
  __shared__ float lred[4];
  const int t = threadIdx.x, w = t >> 6, lane = t & 63;
  float cc = cost_body(Eh, u, v, blockIdx.x);
  if (lane == 0) lred[w] = cc;
  __syncthreads();
  if (t == 0) atomicAdd(&cost[blockIdx.x >> 5], lred[0] + lred[1] + lred[2] + lred[3]);
}

extern "C" void kernel_launch(void* const* d_in, const int* in_sizes, int n_in,
                              void* d_out, int out_size, void* d_ws, size_t ws_size,
                              hipStream_t stream) {
  const float* x = (const float*)d_in[0];
  const float* y = (const float*)d_in[1];
  float* cost = (float*)d_out;

  // workspace layout
  float*  u        = (float*)d_ws;               // 16384
  float*  v        = u + 16384;                  // 16384
  float*  errAcc   = v + 16384;                  // 128
  int*    done     = (int*)(errAcc + 128);       // 32 floats pad
  float*  partials = errAcc + 160;               // 16*16*1024 = 262144
  float*  invnx    = partials + 262144;          // 16384
  float*  invny    = invnx + 16384;              // 16384
  half_t* Eh       = (half_t*)(invny + 16384);   // 16*1024*1024 halfs = 32 MB

  size_t needed = (size_t)(16384*2 + 160 + 262144 + 16384*2) * 4
                + (size_t)16 * 1024 * 1024 * 2;
  if (ws_size < needed) return;  // ~33.3 MB required

  mfa_norms<<<128, 256, 0, stream>>>(x, y, invnx, invny);
  mfa_gemm<<<dim3(8, 8, 16), 256, 0, stream>>>(x, y, invnx, invny, Eh);

  const half_t* Ehc = Eh;
  void* kargs[] = {(void*)&Ehc, (void*)&u, (void*)&v, (void*)&partials,
                   (void*)&errAcc, (void*)&cost};
  hipError_t cerr = hipLaunchCooperativeKernel((const void*)mfa_sinkhorn_coop,
                                               dim3(512), dim3(256), kargs, 0, stream);
  if (cerr != hipSuccess) {
    // Non-cooperative fallback with exact freeze semantics via done flag.
    fb_init<<<129, 256, 0, stream>>>(u, v, errAcc, done, cost);
    for (int it = 0; it < MAX_ITER; ++it) {
      fb_rowpass<<<512, 256, 0, stream>>>(Eh, v, u, errAcc, done, it);
      fb_colpass<<<512, 256, 0, stream>>>(Eh, u, partials, done);
      fb_merge<<<64, 256, 0, stream>>>(partials, v, done);
      fb_check<<<1, 64, 0, stream>>>(errAcc, done, it);
    }
    fb_cost<<<512, 256, 0, stream>>>(Eh, u, v, cost);
  }
}

// Round 3
// 485.086 us; speedup vs baseline: 1.3441x; 1.3441x over previous
//
#include <hip/hip_runtime.h>

typedef _Float16 half_t;
typedef __attribute__((ext_vector_type(8))) _Float16 half8;
typedef __attribute__((ext_vector_type(4))) float f32x4;
typedef __attribute__((ext_vector_type(8))) short short8v;
typedef unsigned short u16;

#define EPS_F      0.1f
#define INV_EPS_F  10.0f
#define MU_F       0.0009765725f  /* 1/1024 + 1e-8 */
#define LOG_MU_F  -6.9314616f
#define LOG_NU_F  -6.9314616f
#define ERR_STOP   1.6f           /* 0.1 * 16 batches (errAcc sums over batches) */
#define MAX_ITER   100
#define SPIN_LIMIT 50000000LL

__device__ __forceinline__ u16 f2bf(float f) {
  unsigned u = __float_as_uint(f);
  return (u16)((u + 0x7fffu + ((u >> 16) & 1u)) >> 16);
}
__device__ __forceinline__ float bf2f(u16 h) {
  return __uint_as_float(((unsigned)h) << 16);
}

// ---------------- K0: init (zero per-call state; harness poisons ws/out) ---
__global__ __launch_bounds__(256) void mfa_init(float* __restrict__ v,
                                                float* __restrict__ u_fb,
                                                float* __restrict__ errAcc,
                                                int* __restrict__ errCnt,
                                                int* __restrict__ bars,
                                                int* __restrict__ done,
                                                float* __restrict__ cost) {
  int g = blockIdx.x * 256 + threadIdx.x;   // grid 64*256 = 16384
  if (g < 16384) { v[g] = 0.0f; u_fb[g] = 0.0f; }
  if (g < 128)   { errAcc[g] = 0.0f; errCnt[g] = 0; }
  if (g < 3200)  bars[g] = 0;
  if (g < 16)    { cost[g] = 0.0f; done[g] = 0; }
}

// ---------------- K1: inverse row norms ----------------
__global__ __launch_bounds__(256) void mfa_norms(const float* __restrict__ x,
                                                 const float* __restrict__ y,
                                                 float* __restrict__ invnx,
                                                 float* __restrict__ invny) {
  int wave = (blockIdx.x * 256 + threadIdx.x) >> 6;
  int lane = threadIdx.x & 63;
  for (int row = wave; row < 32768; row += 512) {
    const float* src = (row < 16384) ? (x + (size_t)row * 256)
                                     : (y + (size_t)(row - 16384) * 256);
    float4 vv = ((const float4*)src)[lane];
    float ss = vv.x*vv.x + vv.y*vv.y + vv.z*vv.z + vv.w*vv.w;
    #pragma unroll
    for (int off = 32; off; off >>= 1) ss += __shfl_xor(ss, off);
    if (lane == 0) {
      float inv = 1.0f / fmaxf(sqrtf(ss), 1e-8f);
      if (row < 16384) invnx[row] = inv; else invny[row - 16384] = inv;
    }
  }
}

// ---------------- K2: MFMA bf16 GEMM -> E(fp16) = 1 - cos ----------------
__global__ __launch_bounds__(256) void mfa_gemm_mfma(const float* __restrict__ X,
                                                     const float* __restrict__ Y,
                                                     const float* __restrict__ invnx,
                                                     const float* __restrict__ invny,
                                                     half_t* __restrict__ Eh) {
  const int b = blockIdx.z;
  const int rowBase = blockIdx.y * 128, colBase = blockIdx.x * 128;
  const float* Xb = X + (size_t)b * 262144;
  const float* Yb = Y + (size_t)b * 262144;

  __shared__ u16 As[128][72];   // bf16, padded stride 72
  __shared__ u16 Bs[128][72];

  const int t = threadIdx.x;
  const int w = t >> 6, lane = t & 63;
  const int wr = w >> 1, wc = w & 1;
  const int fcol = lane & 15, fk = (lane >> 4) << 3;  // frag col/row & k-offset

  f32x4 acc[4][4];
  #pragma unroll
  for (int i = 0; i < 4; ++i)
    #pragma unroll
    for (int j = 0; j < 4; ++j) acc[i][j] = (f32x4){0.f, 0.f, 0.f, 0.f};

  for (int k0 = 0; k0 < 256; k0 += 64) {
    #pragma unroll
    for (int i = 0; i < 8; ++i) {
      int c = t + (i << 8);          // 0..2047
      int row = c >> 4;              // 0..127
      int col = (c & 15) << 2;       // 0..60 step 4
      float sA = invnx[(b << 10) + rowBase + row];
      float4 xa = *(const float4*)(Xb + (size_t)(rowBase + row) * 256 + k0 + col);
      ushort4 ua;
      ua.x = f2bf(xa.x * sA); ua.y = f2bf(xa.y * sA);
      ua.z = f2bf(xa.z * sA); ua.w = f2bf(xa.w * sA);
      *(ushort4*)&As[row][col] = ua;
      float sB = invny[(b << 10) + colBase + row];
      float4 ya = *(const float4*)(Yb + (size_t)(colBase + row) * 256 + k0 + col);
      ushort4 ub;
      ub.x = f2bf(ya.x * sB); ub.y = f2bf(ya.y * sB);
      ub.z = f2bf(ya.z * sB); ub.w = f2bf(ya.w * sB);
      *(ushort4*)&Bs[row][col] = ub;
    }
    __syncthreads();
    #pragma unroll
    for (int kk = 0; kk < 64; kk += 32) {
      short8v a[4], bb[4];
      #pragma unroll
      for (int i = 0; i < 4; ++i)
        a[i] = *(const short8v*)&As[wr*64 + i*16 + fcol][kk + fk];
      #pragma unroll
      for (int j = 0; j < 4; ++j)
        bb[j] = *(const short8v*)&Bs[wc*64 + j*16 + fcol][kk + fk];
      #pragma unroll
      for (int i = 0; i < 4; ++i)
        #pragma unroll
        for (int j = 0; j < 4; ++j)
          acc[i][j] = __builtin_amdgcn_mfma_f32_16x16x32_bf16(a[i], bb[j], acc[i][j], 0, 0, 0);
    }
    __syncthreads();
  }

  // C/D layout: col = lane&15, row = (lane>>4)*4 + reg  [guide-verified]
  const int drow4 = (lane >> 4) << 2;
  #pragma unroll
  for (int i = 0; i < 4; ++i)
    #pragma unroll
    for (int j = 0; j < 4; ++j) {
      int col = colBase + wc*64 + j*16 + fcol;
      #pragma unroll
      for (int q = 0; q < 4; ++q) {
        int row = rowBase + wr*64 + i*16 + drow4 + q;
        Eh[(((size_t)(b << 10) + row) << 10) + col] = (half_t)(1.0f - acc[i][j][q]);
      }
    }
}

// ---------------- batch-local single-use barrier ----------------
__device__ __forceinline__ void bbar(int* ctr, int nblk) {
  __syncthreads();
  if (threadIdx.x == 0) {
    __threadfence();   // release my block's global writes (L2 wb)
    __hip_atomic_fetch_add(ctr, 1, __ATOMIC_ACQ_REL, __HIP_MEMORY_SCOPE_AGENT);
    long long t0 = clock64();
    while (__hip_atomic_load(ctr, __ATOMIC_ACQUIRE, __HIP_MEMORY_SCOPE_AGENT) < nblk) {
      __builtin_amdgcn_s_sleep(2);
      if (clock64() - t0 > SPIN_LIMIT) break;   // watchdog
    }
  }
  __syncthreads();
  __threadfence();     // acquire: invalidate stale caches before reading peers' data
}

// ---------------- K3a: fused Sinkhorn, 256 blocks x 512 threads ----------
// block = (batch b = blk>>4, slice k = blk&15): rows [k*64, k*64+64)
__global__ __launch_bounds__(512, 2) void mfa_sink_fused(
    const half_t* __restrict__ Eh, float* __restrict__ v,
    u16* __restrict__ partials, float* __restrict__ errAcc,
    int* __restrict__ errCnt, int* __restrict__ bars, float* __restrict__ cost) {
  const int t = threadIdx.x, w = t >> 6, lane = t & 63;
  const int blk = blockIdx.x;
  const int b = blk >> 4, k = blk & 15;
  const int rowG0 = (b << 10) + (k << 6) + (w << 3);  // wave's first global row

  __shared__ float cp[8][1024];
  __shared__ float sred[8];
  __shared__ float stopf;

  float ureg[8];
  #pragma unroll
  for (int r = 0; r < 8; ++r) ureg[r] = 0.0f;

  const float* vb = v + (b << 10);
  const float4* vb4 = (const float4*)vb;

  int it = 0;
  for (; it < MAX_ITER; ++it) {
    // ---- load v (16 per lane: m = lane*8+j and 512+lane*8+j) ----
    float4 v0 = vb4[lane*2], v1 = vb4[lane*2 + 1];
    float4 v2 = vb4[128 + lane*2], v3 = vb4[128 + lane*2 + 1];
    float vv[16];
    vv[0]=v0.x; vv[1]=v0.y; vv[2]=v0.z; vv[3]=v0.w;
    vv[4]=v1.x; vv[5]=v1.y; vv[6]=v1.z; vv[7]=v1.w;
    vv[8]=v2.x; vv[9]=v2.y; vv[10]=v2.z; vv[11]=v2.w;
    vv[12]=v3.x; vv[13]=v3.y; vv[14]=v3.z; vv[15]=v3.w;

    float colacc[16];
    #pragma unroll
    for (int j = 0; j < 16; ++j) colacc[j] = 0.0f;
    float werr = 0.0f;

    // ---- fused row pass + column-partial accumulation ----
    #pragma unroll
    for (int r = 0; r < 8; ++r) {
      const half8* E8 = (const half8*)(Eh + ((size_t)(rowG0 + r) << 10));
      half8 ea = E8[lane], eb = E8[lane + 64];
      float rt[16];
      #pragma unroll
      for (int j = 0; j < 8; ++j)
        rt[j] = __expf((vv[j] - (float)ea[j]) * INV_EPS_F);
      #pragma unroll
      for (int j = 0; j < 8; ++j)
        rt[8 + j] = __expf((vv[8 + j] - (float)eb[j]) * INV_EPS_F);
      float s = 0.0f;
      #pragma unroll
      for (int j = 0; j < 16; ++j) s += rt[j];
      #pragma unroll
      for (int off = 32; off; off >>= 1) s += __shfl_xor(s, off);
      float unew = EPS_F * (LOG_MU_F - __logf(s));
      float eu = MU_F / s;                 // exp(u_new/eps)
      werr += fabsf(unew - ureg[r]);
      ureg[r] = unew;
      #pragma unroll
      for (int j = 0; j < 16; ++j) colacc[j] += rt[j] * eu;
    }

    // ---- stage col partials to LDS, reduce across 8 waves ----
    {
      f32x4 c0 = {colacc[0], colacc[1], colacc[2], colacc[3]};
      f32x4 c1 = {colacc[4], colacc[5], colacc[6], colacc[7]};
      f32x4 c2 = {colacc[8], colacc[9], colacc[10], colacc[11]};
      f32x4 c3 = {colacc[12], colacc[13], colacc[14], colacc[15]};
      *(f32x4*)&cp[w][lane*8]       = c0;
      *(f32x4*)&cp[w][lane*8 + 4]   = c1;
      *(f32x4*)&cp[w][512 + lane*8]     = c2;
      *(f32x4*)&cp[w][512 + lane*8 + 4] = c3;
    }
    if (lane == 0) sred[w] = werr;
    __syncthreads();
    {
      int m = t;
      float tot = cp[0][m] + cp[1][m] + cp[2][m] + cp[3][m]
                + cp[4][m] + cp[5][m] + cp[6][m] + cp[7][m];
      partials[(((b << 4) + k) << 10) + m] = f2bf(tot);
      int m2 = t + 512;
      float tot2 = cp[0][m2] + cp[1][m2] + cp[2][m2] + cp[3][m2]
                 + cp[4][m2] + cp[5][m2] + cp[6][m2] + cp[7][m2];
      partials[(((b << 4) + k) << 10) + m2] = f2bf(tot2);
    }
    if (t == 0) {
      float be = sred[0]+sred[1]+sred[2]+sred[3]+sred[4]+sred[5]+sred[6]+sred[7];
      atomicAdd(&errAcc[it], be);
      __threadfence();
      __hip_atomic_fetch_add(&errCnt[it], 1, __ATOMIC_RELEASE, __HIP_MEMORY_SCOPE_AGENT);
    }

    bbar(&bars[((b * MAX_ITER + it) << 1) + 0], 16);   // partials ready (batch)

    // ---- merge: this block owns m in [k*64, k*64+64) ----
    if (t < 64) {
      int m = (k << 6) + t;
      float tot = 0.0f;
      #pragma unroll
      for (int j = 0; j < 16; ++j)
        tot += bf2f(partials[(((b << 4) + j) << 10) + m]);
      v[(b << 10) + m] += EPS_F * (LOG_NU_F - __logf(tot));
    }

    bbar(&bars[((b * MAX_ITER + it) << 1) + 1], 16);   // v ready (batch)

    // ---- lag-1 global stop check (reference freezes after err<thresh) ----
    if (it >= 1) {
      if (t == 0) {
        long long t0 = clock64();
        while (__hip_atomic_load(&errCnt[it-1], __ATOMIC_ACQUIRE,
                                 __HIP_MEMORY_SCOPE_AGENT) < 256) {
          __builtin_amdgcn_s_sleep(2);
          if (clock64() - t0 > SPIN_LIMIT) break;
        }
        float e = __hip_atomic_load(&errAcc[it-1], __ATOMIC_RELAXED,
                                    __HIP_MEMORY_SCOPE_AGENT);
        stopf = (e < ERR_STOP) ? 1.0f : 0.0f;
      }
      __syncthreads();
      bool stop = (stopf != 0.0f);
      __syncthreads();
      if (stop) break;
    }
  }

  // ---- cost pass: cost_b = sum pi*E, pi = exp((u+v-E)/eps) ----
  {
    float4 v0 = vb4[lane*2], v1 = vb4[lane*2 + 1];
    float4 v2 = vb4[128 + lane*2], v3 = vb4[128 + lane*2 + 1];
    float vv[16];
    vv[0]=v0.x; vv[1]=v0.y; vv[2]=v0.z; vv[3]=v0.w;
    vv[4]=v1.x; vv[5]=v1.y; vv[6]=v1.z; vv[7]=v1.w;
    vv[8]=v2.x; vv[9]=v2.y; vv[10]=v2.z; vv[11]=v2.w;
    vv[12]=v3.x; vv[13]=v3.y; vv[14]=v3.z; vv[15]=v3.w;
    float cacc = 0.0f;
    #pragma unroll
    for (int r = 0; r < 8; ++r) {
      const half8* E8 = (const half8*)(Eh + ((size_t)(rowG0 + r) << 10));
      half8 ea = E8[lane], eb = E8[lane + 64];
      float un = ureg[r];
      #pragma unroll
      for (int j = 0; j < 8; ++j) {
        float e = (float)ea[j];
        cacc += __expf((un + vv[j] - e) * INV_EPS_F) * e;
      }
      #pragma unroll
      for (int j = 0; j < 8; ++j) {
        float e = (float)eb[j];
        cacc += __expf((un + vv[8 + j] - e) * INV_EPS_F) * e;
      }
    }
    #pragma unroll
    for (int off = 32; off; off >>= 1) cacc += __shfl_xor(cacc, off);
    if (lane == 0) sred[w] = cacc;
    __syncthreads();
    if (t == 0)
      atomicAdd(&cost[b], sred[0]+sred[1]+sred[2]+sred[3]+sred[4]+sred[5]+sred[6]+sred[7]);
  }
}

// ---------------- K3b fallback (non-coop, fixed 100 rounds w/ done flag) ---
__device__ __forceinline__ float rowpass_body(const half_t* __restrict__ Eh,
                                              const float* __restrict__ v,
                                              float* __restrict__ u, int blk) {
  const int t = threadIdx.x, w = t >> 6, lane = t & 63;
  const int bA = blk >> 5;
  const float4* vb4 = (const float4*)(v + (bA << 10));
  float werr = 0.0f;
  #pragma unroll
  for (int r = 0; r < 8; ++r) {
    const int row = (blk << 5) + (w << 3) + r;
    const half8* E8 = (const half8*)(Eh + ((size_t)row << 10));
    float s = 0.0f;
    #pragma unroll
    for (int q = 0; q < 2; ++q) {
      const int idx = lane + (q << 6);
      half8 e8 = E8[idx];
      float4 va = vb4[idx*2], vc = vb4[idx*2 + 1];
      s += __expf((va.x - (float)e8[0]) * INV_EPS_F);
      s += __expf((va.y - (float)e8[1]) * INV_EPS_F);
      s += __expf((va.z - (float)e8[2]) * INV_EPS_F);
      s += __expf((va.w - (float)e8[3]) * INV_EPS_F);
      s += __expf((vc.x - (float)e8[4]) * INV_EPS_F);
      s += __expf((vc.y - (float)e8[5]) * INV_EPS_F);
      s += __expf((vc.z - (float)e8[6]) * INV_EPS_F);
      s += __expf((vc.w - (float)e8[7]) * INV_EPS_F);
    }
    #pragma unroll
    for (int off = 32; off; off >>= 1) s += __shfl_xor(s, off);
    if (lane == 0) {
      float unew = EPS_F * (LOG_MU_F - __logf(s));
      werr += fabsf(unew - u[row]);
      u[row] = unew;
    }
  }
  return werr;
}

__global__ __launch_bounds__(256) void fb_rowpass(const half_t* __restrict__ Eh,
                                                  const float* __restrict__ v,
                                                  float* __restrict__ u,
                                                  float* __restrict__ errAcc,
                                                  const int* __restrict__ done, int it) {
  if (*done) return;
  __shared__ float lred[4];
  const int t = threadIdx.x, w = t >> 6, lane = t & 63;
  float we = rowpass_body(Eh, v, u, blockIdx.x);
  if (lane == 0) lred[w] = we;
  __syncthreads();
  if (t == 0) atomicAdd(&errAcc[it], lred[0]+lred[1]+lred[2]+lred[3]);
}

__global__ __launch_bounds__(256) void fb_colpass(const half_t* __restrict__ Eh,
                                                  const float* __restrict__ u,
                                                  u16* __restrict__ partials,
                                                  const int* __restrict__ done) {
  if (*done) return;
  const int t = threadIdx.x, blk = blockIdx.x;
  const int b = blk >> 5, sub = blk & 31;
  const int seg = sub & 15, ct = sub >> 4;
  const int m0 = (ct << 9) + (t << 1);
  const float* ub = u + (b << 10);
  const half_t* Eb = Eh + ((size_t)b << 20);
  float p0 = 0.0f, p1 = 0.0f;
  const int n0 = seg << 6;
  #pragma unroll 4
  for (int n = n0; n < n0 + 64; ++n) {
    float un = ub[n];
    const half_t* e = Eb + ((size_t)n << 10) + m0;
    p0 += __expf((un - (float)e[0]) * INV_EPS_F);
    p1 += __expf((un - (float)e[1]) * INV_EPS_F);
  }
  unsigned packed = (unsigned)f2bf(p0) | ((unsigned)f2bf(p1) << 16);
  *(unsigned*)(partials + ((((b << 4) + seg) << 10) + m0)) = packed;
}

__global__ __launch_bounds__(256) void fb_merge(const u16* __restrict__ partials,
                                                float* __restrict__ v,
                                                const int* __restrict__ done) {
  if (*done) return;
  int g = blockIdx.x * 256 + threadIdx.x;
  const int b = g >> 10, m = g & 1023;
  float tot = 0.0f;
  #pragma unroll
  for (int seg = 0; seg < 16; ++seg)
    tot += bf2f(partials[(((b << 4) + seg) << 10) + m]);
  v[g] = EPS_F * (LOG_NU_F - __logf(tot));
}

__global__ void fb_check(const float* __restrict__ errAcc, int* __restrict__ done, int it) {
  if (threadIdx.x == 0 && errAcc[it] < ERR_STOP) *done = 1;
}

__global__ __launch_bounds__(256) void fb_cost(const half_t* __restrict__ Eh,
                                               const float* __restrict__ u,
                                               const float* __restrict__ v,
                                               float* __restrict__ cost) {
  __shared__ float lred[4];
  const int t = threadIdx.x, w = t >> 6, lane = t & 63;
  const int blk = blockIdx.x, bA = blk >> 5;
  const float4* vb4 = (const float4*)(v + (bA << 10));
  float cacc = 0.0f;
  #pragma unroll
  for (int r = 0; r < 8; ++r) {
    const int row = (blk << 5) + (w << 3) + r;
    const float un = u[row];
    const half8* E8 = (const half8*)(Eh + ((size_t)row << 10));
    #pragma unroll
    for (int q = 0; q < 2; ++q) {
      const int idx = lane + (q << 6);
      half8 e8 = E8[idx];
      float4 va = vb4[idx*2], vc = vb4[idx*2 + 1];
      float e;
      e = (float)e8[0]; cacc += __expf((un + va.x - e) * INV_EPS_F) * e;
      e = (float)e8[1]; cacc += __expf((un + va.y - e) * INV_EPS_F) * e;
      e = (float)e8[2]; cacc += __expf((un + va.z - e) * INV_EPS_F) * e;
      e = (float)e8[3]; cacc += __expf((un + va.w - e) * INV_EPS_F) * e;
      e = (float)e8[4]; cacc += __expf((un + vc.x - e) * INV_EPS_F) * e;
      e = (float)e8[5]; cacc += __expf((un + vc.y - e) * INV_EPS_F) * e;
      e = (float)e8[6]; cacc += __expf((un + vc.z - e) * INV_EPS_F) * e;
      e = (float)e8[7]; cacc += __expf((un + vc.w - e) * INV_EPS_F) * e;
    }
  }
  #pragma unroll
  for (int off = 32; off; off >>= 1) cacc += __shfl_xor(cacc, off);
  if (lane == 0) lred[w] = cacc;
  __syncthreads();
  if (t == 0) atomicAdd(&cost[blk >> 5], lred[0]+lred[1]+lred[2]+lred[3]);
}

extern "C" void kernel_launch(void* const* d_in, const int* in_sizes, int n_in,
                              void* d_out, int out_size, void* d_ws, size_t ws_size,
                              hipStream_t stream) {
  const float* x = (const float*)d_in[0];
  const float* y = (const float*)d_in[1];
  float* cost = (float*)d_out;

  // workspace layout (bytes): v | u_fb | errAcc | errCnt | done | bars |
  //                           invnx | invny | partials(bf16) | Eh(fp16)
  char* p = (char*)d_ws;
  float* v        = (float*)p;            p += 16384 * 4;
  float* u_fb     = (float*)p;            p += 16384 * 4;
  float* errAcc   = (float*)p;            p += 128 * 4;
  int*   errCnt   = (int*)p;              p += 128 * 4;
  int*   done     = (int*)p;              p += 16 * 4;
  int*   bars     = (int*)p;              p += 3200 * 4;
  float* invnx    = (float*)p;            p += 16384 * 4;
  float* invny    = (float*)p;            p += 16384 * 4;
  u16*   partials = (u16*)p;              p += 16 * 16 * 1024 * 2;
  half_t* Eh      = (half_t*)p;           p += (size_t)16 * 1024 * 1024 * 2;

  if ((size_t)(p - (char*)d_ws) > ws_size) return;   // ~34.4 MB needed

  mfa_init<<<64, 256, 0, stream>>>(v, u_fb, errAcc, errCnt, bars, done, cost);
  mfa_norms<<<128, 256, 0, stream>>>(x, y, invnx, invny);
  mfa_gemm_mfma<<<dim3(8, 8, 16), 256, 0, stream>>>(x, y, invnx, invny, Eh);

  const half_t* Ehc = Eh;
  void* kargs[] = {(void*)&Ehc, (void*)&v, (void*)&partials, (void*)&errAcc,
                   (void*)&errCnt, (void*)&bars, (void*)&cost};
  hipError_t cerr = hipLaunchCooperativeKernel((const void*)mfa_sink_fused,
                                               dim3(256), dim3(512), kargs, 0, stream);
  if (cerr != hipSuccess) {
    for (int it = 0; it < MAX_ITER; ++it) {
      fb_rowpass<<<512, 256, 0, stream>>>(Eh, v, u_fb, errAcc, done, it);
      fb_colpass<<<512, 256, 0, stream>>>(Eh, u_fb, partials, done);
      fb_merge<<<64, 256, 0, stream>>>(partials, v, done);
      fb_check<<<1, 64, 0, stream>>>(errAcc, done, it);
    }
    fb_cost<<<512, 256, 0, stream>>>(Eh, u_fb, v, cost);
  }
}

// Round 4
// 227.241 us; speedup vs baseline: 2.8692x; 2.1347x over previous
//
#include <hip/hip_runtime.h>

typedef _Float16 half_t;
typedef __attribute__((ext_vector_type(8))) _Float16 half8;
typedef __attribute__((ext_vector_type(4))) float f32x4;
typedef __attribute__((ext_vector_type(8))) short short8v;
typedef unsigned short u16;
typedef unsigned int u32;

// All Sinkhorn math in log2 domain, scaled by S = 10*log2(e).
#define SCALE_F     14.4269504f
#define INV_SCALE_F 0.0693147181f
#define C_MU       -9.99998523f    /* 1.44269504*ln(1/1024+1e-8) */
#define C_NU       -9.99998523f
#define MU_F        0.000976572498f /* 2^C_MU */
#define ERR_STOP_B  1.44269504f    /* 0.1 * SCALE (per-batch stop) */
#define ERR_STOP_G  23.0831206f    /* 1.6 * SCALE (fallback global stop) */
#define MAX_ITER    100
#define SPIN_LIMIT  50000000LL

#define SMEM_E   131072            /* 64*1024 fp16 */
#define SMEM_CP  16384             /* 4*1024 f32   */
#define SMEM_V   4096              /* 1024 f32     */
#define SMEM_RED 256
#define SMEM_TOTAL (SMEM_E + SMEM_CP + SMEM_V + SMEM_RED)

__device__ __forceinline__ float fexp2(float x) { return __builtin_amdgcn_exp2f(x); }
__device__ __forceinline__ float flog2(float x) { return __builtin_amdgcn_logf(x); }

__device__ __forceinline__ u16 f2bf(float f) {
  unsigned u = __float_as_uint(f);
  return (u16)((u + 0x7fffu + ((u >> 16) & 1u)) >> 16);
}
__device__ __forceinline__ float bf2f(u16 h) {
  return __uint_as_float(((unsigned)h) << 16);
}

// ---------------- K0: init ----------------
__global__ __launch_bounds__(256) void mfa_init(float* __restrict__ v,
                                                float* __restrict__ u_fb,
                                                float* __restrict__ errAcc,
                                                float* __restrict__ errB,
                                                int* __restrict__ bars,
                                                int* __restrict__ done,
                                                float* __restrict__ cost) {
  int g = blockIdx.x * 256 + threadIdx.x;   // 64*256 = 16384
  if (g < 16384) { v[g] = 0.0f; u_fb[g] = 0.0f; }
  if (g < 1600)  { errB[g] = 0.0f; bars[g] = 0; }
  if (g < 128)   errAcc[g] = 0.0f;
  if (g < 16)    { cost[g] = 0.0f; done[g] = 0; }
}

// ---------------- K1: inverse row norms ----------------
__global__ __launch_bounds__(256) void mfa_norms(const float* __restrict__ x,
                                                 const float* __restrict__ y,
                                                 float* __restrict__ invnx,
                                                 float* __restrict__ invny) {
  int wave = (blockIdx.x * 256 + threadIdx.x) >> 6;
  int lane = threadIdx.x & 63;
  for (int row = wave; row < 32768; row += 512) {
    const float* src = (row < 16384) ? (x + (size_t)row * 256)
                                     : (y + (size_t)(row - 16384) * 256);
    float4 vv = ((const float4*)src)[lane];
    float ss = vv.x*vv.x + vv.y*vv.y + vv.z*vv.z + vv.w*vv.w;
    #pragma unroll
    for (int off = 32; off; off >>= 1) ss += __shfl_xor(ss, off);
    if (lane == 0) {
      float inv = 1.0f / fmaxf(sqrtf(ss), 1e-8f);
      if (row < 16384) invnx[row] = inv; else invny[row - 16384] = inv;
    }
  }
}

// ---------------- K2: MFMA bf16 GEMM -> E'(fp16) = (1-cos)*SCALE ----------
__global__ __launch_bounds__(256) void mfa_gemm_mfma(const float* __restrict__ X,
                                                     const float* __restrict__ Y,
                                                     const float* __restrict__ invnx,
                                                     const float* __restrict__ invny,
                                                     half_t* __restrict__ Eh) {
  const int b = blockIdx.z;
  const int rowBase = blockIdx.y * 128, colBase = blockIdx.x * 128;
  const float* Xb = X + (size_t)b * 262144;
  const float* Yb = Y + (size_t)b * 262144;

  __shared__ u16 As[128][72];
  __shared__ u16 Bs[128][72];

  const int t = threadIdx.x;
  const int w = t >> 6, lane = t & 63;
  const int wr = w >> 1, wc = w & 1;
  const int fcol = lane & 15, fk = (lane >> 4) << 3;

  f32x4 acc[4][4];
  #pragma unroll
  for (int i = 0; i < 4; ++i)
    #pragma unroll
    for (int j = 0; j < 4; ++j) acc[i][j] = (f32x4){0.f, 0.f, 0.f, 0.f};

  for (int k0 = 0; k0 < 256; k0 += 64) {
    #pragma unroll
    for (int i = 0; i < 8; ++i) {
      int c = t + (i << 8);
      int row = c >> 4;
      int col = (c & 15) << 2;
      float sA = invnx[(b << 10) + rowBase + row];
      float4 xa = *(const float4*)(Xb + (size_t)(rowBase + row) * 256 + k0 + col);
      ushort4 ua;
      ua.x = f2bf(xa.x * sA); ua.y = f2bf(xa.y * sA);
      ua.z = f2bf(xa.z * sA); ua.w = f2bf(xa.w * sA);
      *(ushort4*)&As[row][col] = ua;
      float sB = invny[(b << 10) + colBase + row];
      float4 ya = *(const float4*)(Yb + (size_t)(colBase + row) * 256 + k0 + col);
      ushort4 ub;
      ub.x = f2bf(ya.x * sB); ub.y = f2bf(ya.y * sB);
      ub.z = f2bf(ya.z * sB); ub.w = f2bf(ya.w * sB);
      *(ushort4*)&Bs[row][col] = ub;
    }
    __syncthreads();
    #pragma unroll
    for (int kk = 0; kk < 64; kk += 32) {
      short8v a[4], bb[4];
      #pragma unroll
      for (int i = 0; i < 4; ++i)
        a[i] = *(const short8v*)&As[wr*64 + i*16 + fcol][kk + fk];
      #pragma unroll
      for (int j = 0; j < 4; ++j)
        bb[j] = *(const short8v*)&Bs[wc*64 + j*16 + fcol][kk + fk];
      #pragma unroll
      for (int i = 0; i < 4; ++i)
        #pragma unroll
        for (int j = 0; j < 4; ++j)
          acc[i][j] = __builtin_amdgcn_mfma_f32_16x16x32_bf16(a[i], bb[j], acc[i][j], 0, 0, 0);
    }
    __syncthreads();
  }

  const int drow4 = (lane >> 4) << 2;
  #pragma unroll
  for (int i = 0; i < 4; ++i)
    #pragma unroll
    for (int j = 0; j < 4; ++j) {
      int col = colBase + wc*64 + j*16 + fcol;
      #pragma unroll
      for (int q = 0; q < 4; ++q) {
        int row = rowBase + wr*64 + i*16 + drow4 + q;
        Eh[(((size_t)(b << 10) + row) << 10) + col] =
            (half_t)((1.0f - acc[i][j][q]) * SCALE_F);
      }
    }
}

// ---------------- K3a: LDS-resident Sinkhorn, 256 blocks x 512 thr -------
// block (b = blk>>4, k = blk&15) owns rows [k*64, k*64+64) of batch b.
__global__ __launch_bounds__(512, 1) void mfa_sink_lds(
    const half_t* __restrict__ Eh, u16* __restrict__ partials,
    float* __restrict__ errB, int* __restrict__ bars, float* __restrict__ cost) {
  extern __shared__ char smem[];
  half_t* Els  = (half_t*)smem;                               // [64][1024] E'
  float*  cpb  = (float*)(smem + SMEM_E);                     // [4][1024]
  float*  vsh  = (float*)(smem + SMEM_E + SMEM_CP);           // [1024] v'
  float*  sred = (float*)(smem + SMEM_E + SMEM_CP + SMEM_V);  // [8] + flag

  const int t = threadIdx.x, w = t >> 6, lane = t & 63;
  const int blk = blockIdx.x, b = blk >> 4, k = blk & 15;

  // ---- stage E' slice into LDS (once) ----
  {
    const float4* gsrc = (const float4*)(Eh + ((size_t)((b << 10) + (k << 6)) << 10));
    float4* dst = (float4*)Els;
    #pragma unroll
    for (int i = 0; i < 16; ++i)
      dst[t + (i << 9)] = gsrc[t + (i << 9)];
  }
  vsh[t] = 0.0f; vsh[t + 512] = 0.0f;
  __syncthreads();

  float ureg[8];
  #pragma unroll
  for (int r = 0; r < 8; ++r) ureg[r] = 0.0f;

  const int mlo = lane << 3;           // this lane's low col base
  int it = 0;
  for (; it < MAX_ITER; ++it) {
    // ---- load v' ----
    const f32x4* v4 = (const f32x4*)vsh;
    f32x4 va = v4[lane*2], vb = v4[lane*2 + 1];
    f32x4 vc = v4[128 + lane*2], vd = v4[128 + lane*2 + 1];
    float vv[16];
    vv[0]=va.x; vv[1]=va.y; vv[2]=va.z; vv[3]=va.w;
    vv[4]=vb.x; vv[5]=vb.y; vv[6]=vb.z; vv[7]=vb.w;
    vv[8]=vc.x; vv[9]=vc.y; vv[10]=vc.z; vv[11]=vc.w;
    vv[12]=vd.x; vv[13]=vd.y; vv[14]=vd.z; vv[15]=vd.w;

    float colacc[16];
    #pragma unroll
    for (int j = 0; j < 16; ++j) colacc[j] = 0.0f;
    float werr = 0.0f;

    // ---- fused u-update + col-partial accumulation (E' from LDS) ----
    #pragma unroll
    for (int r = 0; r < 8; ++r) {
      const half8* E8 = (const half8*)(Els + (((w << 3) + r) << 10));
      half8 ea = E8[lane], eb = E8[lane + 64];
      float rt[16];
      float s = 0.0f;
      #pragma unroll
      for (int j = 0; j < 8; ++j) { rt[j] = fexp2(vv[j] - (float)ea[j]); s += rt[j]; }
      #pragma unroll
      for (int j = 0; j < 8; ++j) { rt[8+j] = fexp2(vv[8+j] - (float)eb[j]); s += rt[8+j]; }
      #pragma unroll
      for (int off = 32; off; off >>= 1) s += __shfl_xor(s, off);
      float unew = C_MU - flog2(s);
      float eu = MU_F * __builtin_amdgcn_rcpf(s);   // 2^u'
      werr += fabsf(unew - ureg[r]);
      ureg[r] = unew;
      #pragma unroll
      for (int j = 0; j < 16; ++j) colacc[j] += rt[j] * eu;
    }
    if (lane == 0) sred[w] = werr;

    // ---- 8-wave col reduce via cpb[4][1024] ----
    if (w < 4) {
      #pragma unroll
      for (int j = 0; j < 4; ++j) {
        *(f32x4*)&cpb[w*1024 + mlo + 4*j - ((j>=2)?8:0) + ((j>=2)?512:0)] =
            (f32x4){colacc[4*j], colacc[4*j+1], colacc[4*j+2], colacc[4*j+3]};
      }
    }
    __syncthreads();
    if (w >= 4) {
      const int wb = (w - 4) * 1024;
      #pragma unroll
      for (int j = 0; j < 8; ++j) cpb[wb + mlo + j] += colacc[j];
      #pragma unroll
      for (int j = 0; j < 8; ++j) cpb[wb + 512 + mlo + j] += colacc[8 + j];
    }
    __syncthreads();

    // ---- write bf16 partials (parity double-buffer) ----
    const int p = it & 1;
    const size_t pbase = ((size_t)(((p << 4) | b) << 4 | k) << 10);
    {
      float ta = cpb[t] + cpb[1024 + t] + cpb[2048 + t] + cpb[3072 + t];
      float tb = cpb[512 + t] + cpb[1536 + t] + cpb[2560 + t] + cpb[3584 + t];
      partials[pbase + t]       = f2bf(ta);
      partials[pbase + t + 512] = f2bf(tb);
    }
    __syncthreads();   // all partial writes done

    // ---- per-batch barrier (16 blocks) + err publish ----
    if (t == 0) {
      float be = sred[0]+sred[1]+sred[2]+sred[3]+sred[4]+sred[5]+sred[6]+sred[7];
      atomicAdd(&errB[b * MAX_ITER + it], be);
      __threadfence();
      __hip_atomic_fetch_add(&bars[b * MAX_ITER + it], 1, __ATOMIC_ACQ_REL,
                             __HIP_MEMORY_SCOPE_AGENT);
      long long t0c = clock64();
      while (__hip_atomic_load(&bars[b * MAX_ITER + it], __ATOMIC_ACQUIRE,
                               __HIP_MEMORY_SCOPE_AGENT) < 16) {
        __builtin_amdgcn_s_sleep(1);
        if (clock64() - t0c > SPIN_LIMIT) break;
      }
      sred[8] = errB[b * MAX_ITER + it];   // batch err, complete
    }
    __syncthreads();
    __threadfence();   // acquire: peers' partials
    float errb = sred[8];

    // ---- local v' recompute from all 16 partial slices ----
    {
      float t0s = 0.0f, t1s = 0.0f;
      const u32* pw32 = (const u32*)partials;
      const size_t base32 = ((size_t)(((p << 4) | b) << 4) << 9);  // /2 for u32
      #pragma unroll
      for (int j = 0; j < 16; ++j) {
        u32 pw = pw32[base32 + ((size_t)j << 9) + t];
        t0s += bf2f((u16)(pw & 0xffffu));
        t1s += bf2f((u16)(pw >> 16));
      }
      float v0n = vsh[2*t]     + C_NU - flog2(t0s);
      float v1n = vsh[2*t + 1] + C_NU - flog2(t1s);
      vsh[2*t] = v0n; vsh[2*t + 1] = v1n;
    }
    __syncthreads();

    if (errb < ERR_STOP_B) break;   // per-batch stop (exact same-iteration err)
  }

  // ---- cost pass: cost_b = sum 2^(u'+v'-E') * E' / SCALE ----
  {
    const f32x4* v4 = (const f32x4*)vsh;
    f32x4 va = v4[lane*2], vb = v4[lane*2 + 1];
    f32x4 vc = v4[128 + lane*2], vd = v4[128 + lane*2 + 1];
    float vv[16];
    vv[0]=va.x; vv[1]=va.y; vv[2]=va.z; vv[3]=va.w;
    vv[4]=vb.x; vv[5]=vb.y; vv[6]=vb.z; vv[7]=vb.w;
    vv[8]=vc.x; vv[9]=vc.y; vv[10]=vc.z; vv[11]=vc.w;
    vv[12]=vd.x; vv[13]=vd.y; vv[14]=vd.z; vv[15]=vd.w;
    float cacc = 0.0f;
    #pragma unroll
    for (int r = 0; r < 8; ++r) {
      const half8* E8 = (const half8*)(Els + (((w << 3) + r) << 10));
      half8 ea = E8[lane], eb = E8[lane + 64];
      float un = ureg[r];
      #pragma unroll
      for (int j = 0; j < 8; ++j) {
        float e = (float)ea[j];
        cacc += fexp2(un + vv[j] - e) * e;
      }
      #pragma unroll
      for (int j = 0; j < 8; ++j) {
        float e = (float)eb[j];
        cacc += fexp2(un + vv[8+j] - e) * e;
      }
    }
    #pragma unroll
    for (int off = 32; off; off >>= 1) cacc += __shfl_xor(cacc, off);
    if (lane == 0) sred[w] = cacc;
    __syncthreads();
    if (t == 0)
      atomicAdd(&cost[b], (sred[0]+sred[1]+sred[2]+sred[3]+sred[4]+sred[5]+
                           sred[6]+sred[7]) * INV_SCALE_F);
  }
}

// ---------------- K3b fallback (non-coop, scaled math) ----------------
__global__ __launch_bounds__(256) void fb_rowpass(const half_t* __restrict__ Eh,
                                                  const float* __restrict__ v,
                                                  float* __restrict__ u,
                                                  float* __restrict__ errAcc,
                                                  const int* __restrict__ done, int it) {
  if (*done) return;
  __shared__ float lred[4];
  const int t = threadIdx.x, w = t >> 6, lane = t & 63;
  const int blk = blockIdx.x, bA = blk >> 5;
  const float4* vb4 = (const float4*)(v + (bA << 10));
  float werr = 0.0f;
  #pragma unroll
  for (int r = 0; r < 8; ++r) {
    const int row = (blk << 5) + (w << 3) + r;
    const half8* E8 = (const half8*)(Eh + ((size_t)row << 10));
    float s = 0.0f;
    #pragma unroll
    for (int q = 0; q < 2; ++q) {
      const int idx = lane + (q << 6);
      half8 e8 = E8[idx];
      float4 p0 = vb4[idx*2], p1 = vb4[idx*2 + 1];
      s += fexp2(p0.x - (float)e8[0]) + fexp2(p0.y - (float)e8[1])
         + fexp2(p0.z - (float)e8[2]) + fexp2(p0.w - (float)e8[3])
         + fexp2(p1.x - (float)e8[4]) + fexp2(p1.y - (float)e8[5])
         + fexp2(p1.z - (float)e8[6]) + fexp2(p1.w - (float)e8[7]);
    }
    #pragma unroll
    for (int off = 32; off; off >>= 1) s += __shfl_xor(s, off);
    if (lane == 0) {
      float unew = C_MU - flog2(s);
      werr += fabsf(unew - u[row]);
      u[row] = unew;
    }
  }
  if (lane == 0) lred[w] = werr;
  __syncthreads();
  if (t == 0) atomicAdd(&errAcc[it], lred[0]+lred[1]+lred[2]+lred[3]);
}

__global__ __launch_bounds__(256) void fb_colpass(const half_t* __restrict__ Eh,
                                                  const float* __restrict__ u,
                                                  u16* __restrict__ partials,
                                                  const int* __restrict__ done) {
  if (*done) return;
  const int t = threadIdx.x, blk = blockIdx.x;
  const int b = blk >> 5, sub = blk & 31;
  const int seg = sub & 15, ct = sub >> 4;
  const int m0 = (ct << 9) + (t << 1);
  const float* ub = u + (b << 10);
  const half_t* Eb = Eh + ((size_t)b << 20);
  float p0 = 0.0f, p1 = 0.0f;
  const int n0 = seg << 6;
  #pragma unroll 4
  for (int n = n0; n < n0 + 64; ++n) {
    float un = ub[n];
    const half_t* e = Eb + ((size_t)n << 10) + m0;
    p0 += fexp2(un - (float)e[0]);
    p1 += fexp2(un - (float)e[1]);
  }
  unsigned packed = (unsigned)f2bf(p0) | ((unsigned)f2bf(p1) << 16);
  *(unsigned*)(partials + ((((b << 4) + seg) << 10) + m0)) = packed;
}

__global__ __launch_bounds__(256) void fb_merge(const u16* __restrict__ partials,
                                                float* __restrict__ v,
                                                const int* __restrict__ done) {
  if (*done) return;
  int g = blockIdx.x * 256 + threadIdx.x;
  const int b = g >> 10, m = g & 1023;
  float tot = 0.0f;
  #pragma unroll
  for (int seg = 0; seg < 16; ++seg)
    tot += bf2f(partials[(((b << 4) + seg) << 10) + m]);
  v[g] = C_NU - flog2(tot);
}

__global__ void fb_check(const float* __restrict__ errAcc, int* __restrict__ done, int it) {
  if (threadIdx.x == 0 && errAcc[it] < ERR_STOP_G) *done = 1;
}

__global__ __launch_bounds__(256) void fb_cost(const half_t* __restrict__ Eh,
                                               const float* __restrict__ u,
                                               const float* __restrict__ v,
                                               float* __restrict__ cost) {
  __shared__ float lred[4];
  const int t = threadIdx.x, w = t >> 6, lane = t & 63;
  const int blk = blockIdx.x, bA = blk >> 5;
  const float4* vb4 = (const float4*)(v + (bA << 10));
  float cacc = 0.0f;
  #pragma unroll
  for (int r = 0; r < 8; ++r) {
    const int row = (blk << 5) + (w << 3) + r;
    const float un = u[row];
    const half8* E8 = (const half8*)(Eh + ((size_t)row << 10));
    #pragma unroll
    for (int q = 0; q < 2; ++q) {
      const int idx = lane + (q << 6);
      half8 e8 = E8[idx];
      float4 p0 = vb4[idx*2], p1 = vb4[idx*2 + 1];
      float e;
      e = (float)e8[0]; cacc += fexp2(un + p0.x - e) * e;
      e = (float)e8[1]; cacc += fexp2(un + p0.y - e) * e;
      e = (float)e8[2]; cacc += fexp2(un + p0.z - e) * e;
      e = (float)e8[3]; cacc += fexp2(un + p0.w - e) * e;
      e = (float)e8[4]; cacc += fexp2(un + p1.x - e) * e;
      e = (float)e8[5]; cacc += fexp2(un + p1.y - e) * e;
      e = (float)e8[6]; cacc += fexp2(un + p1.z - e) * e;
      e = (float)e8[7]; cacc += fexp2(un + p1.w - e) * e;
    }
  }
  #pragma unroll
  for (int off = 32; off; off >>= 1) cacc += __shfl_xor(cacc, off);
  if (lane == 0) lred[w] = cacc;
  __syncthreads();
  if (t == 0) atomicAdd(&cost[blk >> 5],
                        (lred[0]+lred[1]+lred[2]+lred[3]) * INV_SCALE_F);
}

extern "C" void kernel_launch(void* const* d_in, const int* in_sizes, int n_in,
                              void* d_out, int out_size, void* d_ws, size_t ws_size,
                              hipStream_t stream) {
  const float* x = (const float*)d_in[0];
  const float* y = (const float*)d_in[1];
  float* cost = (float*)d_out;

  char* p = (char*)d_ws;
  float* v        = (float*)p;            p += 16384 * 4;
  float* u_fb     = (float*)p;            p += 16384 * 4;
  float* errAcc   = (float*)p;            p += 128 * 4;
  float* errB     = (float*)p;            p += 1600 * 4;
  int*   bars     = (int*)p;              p += 1600 * 4;
  int*   done     = (int*)p;              p += 16 * 4;
  float* invnx    = (float*)p;            p += 16384 * 4;
  float* invny    = (float*)p;            p += 16384 * 4;
  u16*   partials = (u16*)p;              p += (size_t)2 * 16 * 16 * 1024 * 2;  // 1 MB
  half_t* Eh      = (half_t*)p;           p += (size_t)16 * 1024 * 1024 * 2;    // 32 MB

  if ((size_t)(p - (char*)d_ws) > ws_size) return;

  mfa_init<<<64, 256, 0, stream>>>(v, u_fb, errAcc, errB, bars, done, cost);
  mfa_norms<<<128, 256, 0, stream>>>(x, y, invnx, invny);
  mfa_gemm_mfma<<<dim3(8, 8, 16), 256, 0, stream>>>(x, y, invnx, invny, Eh);

  (void)hipFuncSetAttribute((const void*)mfa_sink_lds,
                            hipFuncAttributeMaxDynamicSharedMemorySize, SMEM_TOTAL);
  const half_t* Ehc = Eh;
  void* kargs[] = {(void*)&Ehc, (void*)&partials, (void*)&errB,
                   (void*)&bars, (void*)&cost};
  hipError_t cerr = hipLaunchCooperativeKernel((const void*)mfa_sink_lds,
                                               dim3(256), dim3(512), kargs,
                                               SMEM_TOTAL, stream);
  if (cerr != hipSuccess) {
    for (int it = 0; it < MAX_ITER; ++it) {
      fb_rowpass<<<512, 256, 0, stream>>>(Eh, v, u_fb, errAcc, done, it);
      fb_colpass<<<512, 256, 0, stream>>>(Eh, u_fb, partials, done);
      fb_merge<<<64, 256, 0, stream>>>(partials, v, done);
      fb_check<<<1, 64, 0, stream>>>(errAcc, done, it);
    }
    fb_cost<<<512, 256, 0, stream>>>(Eh, u_fb, v, cost);
  }
}